// Round 4
// baseline (8624.568 us; speedup 1.0000x reference)
//
#include <hip/hip_runtime.h>

typedef _Float16 f16x8 __attribute__((ext_vector_type(8)));
typedef float f32x4 __attribute__((ext_vector_type(4)));

#define VOCAB 128
#define EMB 512
#define HID 1024
#define BATCH 256
#define TSEQ 256

#define SLOT (BATCH * HID)            // elems per ring slot (f16 for h, f32 for pre1)

// ---- workspace byte offsets ----
#define CTR0_B 0                      // 256 u32
#define CTRG_B 1024
#define CTR1_B 2048
#define H0_B   4096                               // 4 slots * SLOT * 2B = 2 MB
#define H1_B   (H0_B + 4 * SLOT * 2)              // 2 MB
#define PRE1_B (H1_B + 4 * SLOT * 2)              // 4 slots * SLOT * 4B = 4 MB
#define PROJ_B (PRE1_B + 4 * SLOT * 4)            // 128*1024*4 = 512 KB
#define WIMG_B (PROJ_B + VOCAB * HID * 4)         // 3 roles * 32 cb * 65536 f16 = 12.58 MB

__device__ __forceinline__ f32x4 mfma16(f16x8 a, f16x8 b, f32x4 c) {
    return __builtin_amdgcn_mfma_f32_16x16x32_f16(a, b, c, 0, 0, 0);
}

// ---- pack one 1024x1024 f32 weight matrix into the swizzled LDS image (hi+lo f16) ----
// image layout per (cb): [half][brow 0..31][chunk' 0..127][8 f16], chunk' = chunk ^ (brow&7)
__global__ __launch_bounds__(256) void pack_w(const float* __restrict__ W,
                                              _Float16* __restrict__ img) {
    int i = blockIdx.x * 256 + threadIdx.x;
    if (i >= HID * 128) return;
    const int n = i >> 7;          // weight row (output col) 0..1023
    const int c = i & 127;         // 16B chunk (8 f16) within K
    const int cb = n >> 5;
    const int brow = n & 31;
    const float* src = W + (size_t)n * HID + c * 8;
    float4 u0 = *(const float4*)src;
    float4 u1 = *(const float4*)(src + 4);
    float uf[8] = {u0.x, u0.y, u0.z, u0.w, u1.x, u1.y, u1.z, u1.w};
    f16x8 hi, lo;
    #pragma unroll
    for (int j = 0; j < 8; ++j) {
        _Float16 h = (_Float16)uf[j];
        hi[j] = h;
        lo[j] = (_Float16)(uf[j] - (float)h);
    }
    const size_t base = (size_t)cb * 65536 + (size_t)brow * 1024 +
                        (size_t)((c ^ (brow & 7)) * 8);
    *(f16x8*)(img + base)         = hi;
    *(f16x8*)(img + base + 32768) = lo;
}

// ---- PROJ[v][n] = emb[v,:] . Wih0[n,:] + b_ih0[n]  (f32 exact) ----
__global__ __launch_bounds__(256) void proj_k(const float* __restrict__ emb,
                                              const float* __restrict__ Wih0,
                                              const float* __restrict__ b_ih0,
                                              float* __restrict__ PROJ) {
    int o = blockIdx.x * 256 + threadIdx.x;
    if (o >= VOCAB * HID) return;
    const int v = o >> 10, n = o & (HID - 1);
    const float* er = emb + (size_t)v * EMB;
    const float* wr = Wih0 + (size_t)n * EMB;
    float acc = 0.f;
    #pragma unroll 4
    for (int k = 0; k < EMB; k += 4) {
        float4 e = *(const float4*)(er + k);
        float4 w = *(const float4*)(wr + k);
        acc += e.x * w.x + e.y * w.y + e.z * w.z + e.w * w.w;
    }
    PROJ[o] = acc + b_ih0[n];
}

__device__ __forceinline__ void spin64(const unsigned int* p) {
    while (__hip_atomic_load(p, __ATOMIC_ACQUIRE, __HIP_MEMORY_SCOPE_AGENT) < 64u)
        __builtin_amdgcn_s_sleep(4);
}

// ---- persistent RNN: 192 blocks (3 roles x 2 row-groups x 32 col-blocks) ----
// role 0: h0[t] = tanh(h0[t-1]@Whh0^T + PROJ[tok] + b_hh0)
// role 1: pre1[u] = h0[u]@Wih1^T + b_ih1
// role 2: h1[v] = tanh(h1[v-1]@Whh1^T + pre1[v] + b_hh1)
__global__ __launch_bounds__(256, 1) void rnn_run(
    const int* __restrict__ tokens,
    const float* __restrict__ b_hh0, const float* __restrict__ b_ih1,
    const float* __restrict__ b_hh1, char* __restrict__ ws)
{
    __shared__ _Float16 simg[65536];   // 128 KB: [2 half][32 rows][128 chunks][8 f16]

    unsigned int* ctr0 = (unsigned int*)(ws + CTR0_B);
    unsigned int* ctrG = (unsigned int*)(ws + CTRG_B);
    unsigned int* ctr1 = (unsigned int*)(ws + CTR1_B);
    _Float16* h0 = (_Float16*)(ws + H0_B);
    _Float16* h1 = (_Float16*)(ws + H1_B);
    float* pre1 = (float*)(ws + PRE1_B);
    const float* PROJ = (const float*)(ws + PROJ_B);
    const _Float16* wimg = (const _Float16*)(ws + WIMG_B);

    const int tid = threadIdx.x, lane = tid & 63, wv = tid >> 6;
    const int blk = blockIdx.x;
    const int role = blk >> 6;           // 0,1,2
    const int sub = blk & 63;
    const int cb = sub & 31, rg = sub >> 5;
    const int n0 = cb * 32;

    // stage this block's weight image into LDS (linear copy; swizzle baked in)
    {
        const _Float16* gi = wimg + (size_t)(role * 32 + cb) * 65536;
        for (int i = tid; i < 8192; i += 256)
            *(f16x8*)&simg[(size_t)i * 8] = *(const f16x8*)&gi[(size_t)i * 8];
    }
    __syncthreads();

    const int ar = lane & 15;            // frag row/col
    const int g16 = lane >> 4;           // 0..3
    const int akb = g16 * 8;             // k offset within 32
    const int rbase = rg * 128 + wv * 32;

    const float* bias = (role == 0) ? b_hh0 : (role == 1) ? b_ih1 : b_hh1;
    const float b0 = bias[n0 + ar];
    const float b1 = bias[n0 + 16 + ar];
    unsigned int* ctr_pub = (role == 0) ? ctr0 : (role == 1) ? ctrG : ctr1;

    for (int st = 0; st < TSEQ; ++st) {
        // ---- waits (RAW + WAR with depth-4 rings) ----
        if (tid == 0) {
            if (role == 0) {
                if (st)      spin64(ctr0 + st - 1);
                if (st >= 4) spin64(ctrG + st - 4);
            } else if (role == 1) {
                spin64(ctr0 + st);
                if (st >= 4) spin64(ctr1 + st - 4);
            } else {
                spin64(ctrG + st);
                if (st)      spin64(ctr1 + st - 1);
            }
        }
        __syncthreads();

        const _Float16* A = (role == 0) ? h0 + (size_t)((st + 3) & 3) * SLOT
                          : (role == 1) ? h0 + (size_t)(st & 3) * SLOT
                                        : h1 + (size_t)((st + 3) & 3) * SLOT;
        const _Float16* Ar0 = A + (size_t)(rbase + ar) * HID + akb;

        f32x4 a00 = {}, a01 = {}, a10 = {}, a11 = {};
        #pragma unroll 8
        for (int kc = 0; kc < 32; ++kc) {
            f16x8 av0 = *(const f16x8*)(Ar0 + kc * 32);
            f16x8 av1 = *(const f16x8*)(Ar0 + 16 * HID + kc * 32);
            const int sw = ((kc * 4 + g16) ^ (ar & 7)) * 8;
            f16x8 bh0 = *(const f16x8*)&simg[ar * 1024 + sw];
            f16x8 bh1 = *(const f16x8*)&simg[(16 + ar) * 1024 + sw];
            f16x8 bl0 = *(const f16x8*)&simg[32768 + ar * 1024 + sw];
            f16x8 bl1 = *(const f16x8*)&simg[32768 + (16 + ar) * 1024 + sw];
            a00 = mfma16(av0, bh0, a00);
            a01 = mfma16(av0, bh1, a01);
            a10 = mfma16(av1, bh0, a10);
            a11 = mfma16(av1, bh1, a11);
            a00 = mfma16(av0, bl0, a00);
            a01 = mfma16(av0, bl1, a01);
            a10 = mfma16(av1, bl0, a10);
            a11 = mfma16(av1, bl1, a11);
        }

        // ---- epilogue ----
        if (role == 0) {
            _Float16* O = h0 + (size_t)(st & 3) * SLOT;
            #pragma unroll
            for (int mf = 0; mf < 2; ++mf) {
                #pragma unroll
                for (int r = 0; r < 4; ++r) {
                    const int rr = rbase + mf * 16 + g16 * 4 + r;
                    const int tok = tokens[rr * TSEQ + st];
                    const float* pr = PROJ + (size_t)tok * HID + n0;
                    const float v0 = (mf ? a10[r] : a00[r]) + pr[ar] + b0;
                    const float v1 = (mf ? a11[r] : a01[r]) + pr[16 + ar] + b1;
                    O[(size_t)rr * HID + n0 + ar]      = (_Float16)tanhf(v0);
                    O[(size_t)rr * HID + n0 + 16 + ar] = (_Float16)tanhf(v1);
                }
            }
        } else if (role == 1) {
            float* O = pre1 + (size_t)(st & 3) * SLOT;
            #pragma unroll
            for (int mf = 0; mf < 2; ++mf) {
                #pragma unroll
                for (int r = 0; r < 4; ++r) {
                    const int rr = rbase + mf * 16 + g16 * 4 + r;
                    O[(size_t)rr * HID + n0 + ar]      = (mf ? a10[r] : a00[r]) + b0;
                    O[(size_t)rr * HID + n0 + 16 + ar] = (mf ? a11[r] : a01[r]) + b1;
                }
            }
        } else {
            const float* P = pre1 + (size_t)(st & 3) * SLOT;
            _Float16* O = h1 + (size_t)(st & 3) * SLOT;
            #pragma unroll
            for (int mf = 0; mf < 2; ++mf) {
                #pragma unroll
                for (int r = 0; r < 4; ++r) {
                    const int rr = rbase + mf * 16 + g16 * 4 + r;
                    const size_t o0 = (size_t)rr * HID + n0 + ar;
                    const size_t o1 = o0 + 16;
                    const float v0 = (mf ? a10[r] : a00[r]) + P[o0] + b0;
                    const float v1 = (mf ? a11[r] : a01[r]) + P[o1] + b1;
                    O[o0] = (_Float16)tanhf(v0);
                    O[o1] = (_Float16)tanhf(v1);
                }
            }
        }

        __syncthreads();   // drains all stores (vmcnt 0) before publish
        if (tid == 0)
            __hip_atomic_fetch_add(ctr_pub + st, 1u, __ATOMIC_RELEASE,
                                   __HIP_MEMORY_SCOPE_AGENT);
    }
}

// ---- head: out[m][n] = h1[255][m,:] . Wout[n,:] + b_out[n] ----
__global__ __launch_bounds__(256) void head2(const _Float16* __restrict__ h1last,
                                             const float* __restrict__ Wout,
                                             const float* __restrict__ b_out,
                                             float* __restrict__ out) {
    const int idx = blockIdx.x * 256 + threadIdx.x;   // 32768
    const int m = idx >> 7, n = idx & 127;
    const _Float16* hr = h1last + (size_t)m * HID;
    const float* wr = Wout + (size_t)n * HID;
    float acc = 0.f;
    #pragma unroll 4
    for (int k = 0; k < HID; k += 8) {
        f16x8 hv = *(const f16x8*)(hr + k);
        float4 w0 = *(const float4*)(wr + k);
        float4 w1 = *(const float4*)(wr + k + 4);
        acc += (float)hv[0] * w0.x + (float)hv[1] * w0.y +
               (float)hv[2] * w0.z + (float)hv[3] * w0.w +
               (float)hv[4] * w1.x + (float)hv[5] * w1.y +
               (float)hv[6] * w1.z + (float)hv[7] * w1.w;
    }
    out[idx] = acc + b_out[n];
}

extern "C" void kernel_launch(void* const* d_in, const int* in_sizes, int n_in,
                              void* d_out, int out_size, void* d_ws, size_t ws_size,
                              hipStream_t stream) {
    const int*   tokens = (const int*)  d_in[0];
    const float* emb    = (const float*)d_in[1];
    const float* W_ih0  = (const float*)d_in[2];
    const float* W_hh0  = (const float*)d_in[3];
    const float* b_ih0  = (const float*)d_in[4];
    const float* b_hh0  = (const float*)d_in[5];
    const float* W_ih1  = (const float*)d_in[6];
    const float* W_hh1  = (const float*)d_in[7];
    const float* b_ih1  = (const float*)d_in[8];
    const float* b_hh1  = (const float*)d_in[9];
    const float* W_out  = (const float*)d_in[10];
    const float* b_out  = (const float*)d_in[11];
    float* out = (float*)d_out;

    char* ws = (char*)d_ws;
    _Float16* wimg = (_Float16*)(ws + WIMG_B);
    float* PROJ = (float*)(ws + PROJ_B);

    // zero counters + the t=-1 ring slots (slot 3 of h0 and h1)
    hipMemsetAsync(ws + CTR0_B, 0, 4096, stream);
    hipMemsetAsync(ws + H0_B + (size_t)3 * SLOT * 2, 0, (size_t)SLOT * 2, stream);
    hipMemsetAsync(ws + H1_B + (size_t)3 * SLOT * 2, 0, (size_t)SLOT * 2, stream);

    // pack weight images (role 0: Whh0, role 1: Wih1, role 2: Whh1)
    pack_w<<<512, 256, 0, stream>>>(W_hh0, wimg);
    pack_w<<<512, 256, 0, stream>>>(W_ih1, wimg + (size_t)32 * 65536);
    pack_w<<<512, 256, 0, stream>>>(W_hh1, wimg + (size_t)64 * 65536);
    // fused input projection table (exact f32)
    proj_k<<<512, 256, 0, stream>>>(emb, W_ih0, b_ih0, PROJ);

    // persistent pipelined RNN (192 blocks, 1/CU, flag-synced)
    rnn_run<<<192, 256, 0, stream>>>(tokens, b_hh0, b_ih1, b_hh1, ws);

    // head from h1[255] (ring slot 3)
    head2<<<128, 256, 0, stream>>>((const _Float16*)(ws + H1_B) + (size_t)3 * SLOT,
                                   W_out, b_out, out);
}

// Round 5
// 6264.613 us; speedup vs baseline: 1.3767x; 1.3767x over previous
//
#include <hip/hip_runtime.h>

typedef _Float16 f16x8 __attribute__((ext_vector_type(8)));
typedef float f32x4 __attribute__((ext_vector_type(4)));

#define VOCAB 128
#define EMB 512
#define HID 1024
#define BATCH 256
#define TSEQ 256
#define SLOT (BATCH * HID)

// ---- workspace byte offsets ----
#define CTR0_B 0                                  // 256 u32
#define CTRG_B 1024
#define CTR1_B 2048
#define H0_B   4096                               // 4 slots * SLOT * 2B
#define H1_B   (H0_B + 4 * SLOT * 2)
#define PRE1_B (H1_B + 4 * SLOT * 2)              // 4 slots * SLOT * 4B
#define PROJ_B (PRE1_B + 4 * SLOT * 4)            // 128*1024*4
#define WIMG_B (PROJ_B + VOCAB * HID * 4)         // 3*32*65536 f16

// ---- device-scope (bypass L1/L2, LLC-coherent) memory ops ----
#define LOADX4(dst, p) asm volatile("global_load_dwordx4 %0, %1, off sc0 sc1" : "=v"(dst) : "v"(p))
#define LOADD(dst, p)  asm volatile("global_load_dword %0, %1, off sc0 sc1" : "=v"(dst) : "v"(p))
#define STORES(p, u)   asm volatile("global_store_short %0, %1, off sc0 sc1" :: "v"(p), "v"(u) : "memory")
#define STORED(p, u)   asm volatile("global_store_dword %0, %1, off sc0 sc1" :: "v"(p), "v"(u) : "memory")
#define WAITV(n) do { asm volatile("s_waitcnt vmcnt(" #n ")" ::: "memory"); \
                      __builtin_amdgcn_sched_barrier(0); } while (0)

__device__ __forceinline__ f32x4 mfma16(f16x8 a, f16x8 b, f32x4 c) {
    return __builtin_amdgcn_mfma_f32_16x16x32_f16(a, b, c, 0, 0, 0);
}

__device__ __forceinline__ void store_h(_Float16* p, float v) {
    _Float16 h = (_Float16)v;
    unsigned short s;
    __builtin_memcpy(&s, &h, 2);
    unsigned int u = s;
    STORES(p, u);
}

__device__ __forceinline__ void spin64(unsigned int* p) {
    while (__hip_atomic_load(p, __ATOMIC_RELAXED, __HIP_MEMORY_SCOPE_AGENT) < 64u)
        __builtin_amdgcn_s_sleep(1);
}

// ---- pack one 1024x1024 f32 weight matrix into the LDS image (hi+lo f16) ----
// per col-block cb: [kc 0..31][half][nf 0..1][g16 0..3][ar 0..15][8 f16]
// -> in-kernel read addr = kc*2048 + half*1024 + nf*512 + lane*8 (fully linear in lane)
__global__ __launch_bounds__(256) void pack_w(const float* __restrict__ W,
                                              _Float16* __restrict__ img) {
    int i = blockIdx.x * 256 + threadIdx.x;
    if (i >= HID * 128) return;
    const int n = i >> 7;          // weight row (output col) 0..1023
    const int c = i & 127;         // 8-elem k-chunk
    const int cb = n >> 5;
    const int col = n & 31;
    const int nf = col >> 4, ar = col & 15;
    const int kc = c >> 2, g = c & 3;
    const float* src = W + (size_t)n * HID + c * 8;
    float4 u0 = *(const float4*)src;
    float4 u1 = *(const float4*)(src + 4);
    float uf[8] = {u0.x, u0.y, u0.z, u0.w, u1.x, u1.y, u1.z, u1.w};
    f16x8 hi, lo;
    #pragma unroll
    for (int j = 0; j < 8; ++j) {
        _Float16 h = (_Float16)uf[j];
        hi[j] = h;
        lo[j] = (_Float16)(uf[j] - (float)h);
    }
    const size_t base = (size_t)cb * 65536 + (size_t)kc * 2048 +
                        (size_t)nf * 512 + (size_t)g * 128 + (size_t)ar * 8;
    *(f16x8*)(img + base)        = hi;
    *(f16x8*)(img + base + 1024) = lo;
}

// ---- PROJ[v][n] = emb[v,:] . Wih0[n,:] + b_ih0[n]  (f32 exact) ----
__global__ __launch_bounds__(256) void proj_k(const float* __restrict__ emb,
                                              const float* __restrict__ Wih0,
                                              const float* __restrict__ b_ih0,
                                              float* __restrict__ PROJ) {
    int o = blockIdx.x * 256 + threadIdx.x;
    if (o >= VOCAB * HID) return;
    const int v = o >> 10, n = o & (HID - 1);
    const float* er = emb + (size_t)v * EMB;
    const float* wr = Wih0 + (size_t)n * EMB;
    float acc = 0.f;
    #pragma unroll 4
    for (int k = 0; k < EMB; k += 4) {
        float4 e = *(const float4*)(er + k);
        float4 w = *(const float4*)(wr + k);
        acc += e.x * w.x + e.y * w.y + e.z * w.z + e.w * w.w;
    }
    PROJ[o] = acc + b_ih0[n];
}

// ---- persistent RNN: 192 blocks (3 roles x 2 row-groups x 32 col-blocks) ----
#define ISSUE4(B0, B1, KCB) do { \
    const _Float16* q0_ = pr0 + (KCB) * 32; \
    const _Float16* q1_ = pr1 + (KCB) * 32; \
    LOADX4(B0[0], q0_);      LOADX4(B0[1], q0_ + 32); \
    LOADX4(B0[2], q0_ + 64); LOADX4(B0[3], q0_ + 96); \
    LOADX4(B1[0], q1_);      LOADX4(B1[1], q1_ + 32); \
    LOADX4(B1[2], q1_ + 64); LOADX4(B1[3], q1_ + 96); \
} while (0)

#define KC1(KC, AV0, AV1) do { \
    const _Float16* sb_ = simg + (KC) * 2048 + lane * 8; \
    f16x8 bh0_ = *(const f16x8*)sb_; \
    f16x8 bh1_ = *(const f16x8*)(sb_ + 512); \
    f16x8 bl0_ = *(const f16x8*)(sb_ + 1024); \
    f16x8 bl1_ = *(const f16x8*)(sb_ + 1536); \
    a00 = mfma16(AV0, bh0_, a00); a01 = mfma16(AV0, bh1_, a01); \
    a10 = mfma16(AV1, bh0_, a10); a11 = mfma16(AV1, bh1_, a11); \
    a00 = mfma16(AV0, bl0_, a00); a01 = mfma16(AV0, bl1_, a01); \
    a10 = mfma16(AV1, bl0_, a10); a11 = mfma16(AV1, bl1_, a11); \
} while (0)

#define KC4(KB, CB0, CB1) do { \
    KC1((KB) + 0, CB0[0], CB1[0]); \
    KC1((KB) + 1, CB0[1], CB1[1]); \
    KC1((KB) + 2, CB0[2], CB1[2]); \
    KC1((KB) + 3, CB0[3], CB1[3]); \
} while (0)

__global__ __launch_bounds__(256, 1) void rnn_run(
    const int* __restrict__ tokens,
    const float* __restrict__ b_hh0, const float* __restrict__ b_ih1,
    const float* __restrict__ b_hh1, char* __restrict__ ws)
{
    __shared__ _Float16 simg[65536];   // 128 KB weight slice (hi+lo)

    unsigned int* ctr0 = (unsigned int*)(ws + CTR0_B);
    unsigned int* ctrG = (unsigned int*)(ws + CTRG_B);
    unsigned int* ctr1 = (unsigned int*)(ws + CTR1_B);
    _Float16* h0 = (_Float16*)(ws + H0_B);
    _Float16* h1 = (_Float16*)(ws + H1_B);
    float* pre1 = (float*)(ws + PRE1_B);
    const float* PROJ = (const float*)(ws + PROJ_B);
    const _Float16* wimg = (const _Float16*)(ws + WIMG_B);

    const int tid = threadIdx.x, lane = tid & 63, wv = tid >> 6;
    const int blk = blockIdx.x;
    const int role = blk >> 6;           // 0,1,2
    const int sub = blk & 63;
    const int cb = sub & 31, rg = sub >> 5;
    const int n0 = cb * 32;

    // stage weight slice into LDS (read-only, normally cached)
    {
        const _Float16* gi = wimg + (size_t)(role * 32 + cb) * 65536;
        for (int i = tid; i < 8192; i += 256)
            *(f16x8*)&simg[(size_t)i * 8] = *(const f16x8*)&gi[(size_t)i * 8];
    }
    __syncthreads();

    const int ar = lane & 15;
    const int g16 = lane >> 4;
    const int rbase = rg * 128 + wv * 32;
    const int er0 = rbase + g16 * 4;

    const float* bias = (role == 0) ? b_hh0 : (role == 1) ? b_ih1 : b_hh1;
    const float b0 = bias[n0 + ar];
    const float b1 = bias[n0 + 16 + ar];
    unsigned int* ctr_pub = (role == 0) ? ctr0 : (role == 1) ? ctrG : ctr1;

    for (int st = 0; st < TSEQ; ++st) {
        // ---- waits (RAW + WAR, depth-4 rings); relaxed polls = no cache inv ----
        if (tid == 0) {
            if (role == 0) {
                if (st)      spin64(ctr0 + st - 1);
                if (st >= 4) spin64(ctrG + st - 4);
            } else if (role == 1) {
                spin64(ctr0 + st);
                if (st >= 4) spin64(ctr1 + st - 4);
            } else {
                spin64(ctrG + st);
                if (st)      spin64(ctr1 + st - 1);
            }
        }
        __syncthreads();

        const _Float16* A = (role == 0) ? h0 + (size_t)((st + 3) & 3) * SLOT
                          : (role == 1) ? h0 + (size_t)(st & 3) * SLOT
                                        : h1 + (size_t)((st + 3) & 3) * SLOT;
        const _Float16* pr0 = A + (size_t)(rbase + ar) * HID + g16 * 8;
        const _Float16* pr1 = pr0 + 16 * HID;

        f32x4 a00 = {}, a01 = {}, a10 = {}, a11 = {};
        f16x8 ca0[4], ca1[4], cb0[4], cb1[4];

        __builtin_amdgcn_sched_barrier(0);
        ISSUE4(ca0, ca1, 0);
        #pragma unroll
        for (int k8 = 0; k8 < 4; ++k8) {
            const int kb = k8 * 8;
            ISSUE4(cb0, cb1, kb + 4);
            WAITV(8);
            KC4(kb, ca0, ca1);
            if (k8 < 3) {
                ISSUE4(ca0, ca1, kb + 8);
                WAITV(8);
            } else {
                WAITV(0);
            }
            KC4(kb + 4, cb0, cb1);
        }
        __builtin_amdgcn_sched_barrier(0);

        // ---- epilogue (device-scope write-through stores) ----
        if (role == 0) {
            _Float16* O = h0 + (size_t)(st & 3) * SLOT;
            #pragma unroll
            for (int mf = 0; mf < 2; ++mf) {
                #pragma unroll
                for (int r = 0; r < 4; ++r) {
                    const int rr = er0 + mf * 16 + r;
                    const int tok = tokens[rr * TSEQ + st];
                    const float* pr = PROJ + (size_t)tok * HID + n0;
                    const float v0 = (mf ? a10[r] : a00[r]) + pr[ar] + b0;
                    const float v1 = (mf ? a11[r] : a01[r]) + pr[16 + ar] + b1;
                    store_h(O + (size_t)rr * HID + n0 + ar, tanhf(v0));
                    store_h(O + (size_t)rr * HID + n0 + 16 + ar, tanhf(v1));
                }
            }
        } else if (role == 1) {
            float* O = pre1 + (size_t)(st & 3) * SLOT;
            #pragma unroll
            for (int mf = 0; mf < 2; ++mf) {
                #pragma unroll
                for (int r = 0; r < 4; ++r) {
                    const int rr = er0 + mf * 16 + r;
                    const float v0 = (mf ? a10[r] : a00[r]) + b0;
                    const float v1 = (mf ? a11[r] : a01[r]) + b1;
                    STORED(O + (size_t)rr * HID + n0 + ar, v0);
                    STORED(O + (size_t)rr * HID + n0 + 16 + ar, v1);
                }
            }
        } else {
            const float* P = pre1 + (size_t)(st & 3) * SLOT;
            float pv0[8], pv1[8];
            #pragma unroll
            for (int mf = 0; mf < 2; ++mf) {
                #pragma unroll
                for (int r = 0; r < 4; ++r) {
                    const int rr = er0 + mf * 16 + r;
                    LOADD(pv0[mf * 4 + r], P + (size_t)rr * HID + n0 + ar);
                    LOADD(pv1[mf * 4 + r], P + (size_t)rr * HID + n0 + 16 + ar);
                }
            }
            WAITV(0);
            _Float16* O = h1 + (size_t)(st & 3) * SLOT;
            #pragma unroll
            for (int mf = 0; mf < 2; ++mf) {
                #pragma unroll
                for (int r = 0; r < 4; ++r) {
                    const int rr = er0 + mf * 16 + r;
                    const float v0 = (mf ? a10[r] : a00[r]) + pv0[mf * 4 + r] + b0;
                    const float v1 = (mf ? a11[r] : a01[r]) + pv1[mf * 4 + r] + b1;
                    store_h(O + (size_t)rr * HID + n0 + ar, tanhf(v0));
                    store_h(O + (size_t)rr * HID + n0 + 16 + ar, tanhf(v1));
                }
            }
        }

        asm volatile("s_waitcnt vmcnt(0)" ::: "memory");   // per-wave store drain
        __syncthreads();
        if (tid == 0)
            __hip_atomic_fetch_add(ctr_pub + st, 1u, __ATOMIC_RELEASE,
                                   __HIP_MEMORY_SCOPE_AGENT);
    }
}

// ---- head: out[m][n] = h1[255][m,:] . Wout[n,:] + b_out[n] ----
__global__ __launch_bounds__(256) void head2(const _Float16* __restrict__ h1last,
                                             const float* __restrict__ Wout,
                                             const float* __restrict__ b_out,
                                             float* __restrict__ out) {
    const int idx = blockIdx.x * 256 + threadIdx.x;   // 32768
    const int m = idx >> 7, n = idx & 127;
    const _Float16* hr = h1last + (size_t)m * HID;
    const float* wr = Wout + (size_t)n * HID;
    float acc = 0.f;
    #pragma unroll 4
    for (int k = 0; k < HID; k += 8) {
        f16x8 hv = *(const f16x8*)(hr + k);
        float4 w0 = *(const float4*)(wr + k);
        float4 w1 = *(const float4*)(wr + k + 4);
        acc += (float)hv[0] * w0.x + (float)hv[1] * w0.y +
               (float)hv[2] * w0.z + (float)hv[3] * w0.w +
               (float)hv[4] * w1.x + (float)hv[5] * w1.y +
               (float)hv[6] * w1.z + (float)hv[7] * w1.w;
    }
    out[idx] = acc + b_out[n];
}

extern "C" void kernel_launch(void* const* d_in, const int* in_sizes, int n_in,
                              void* d_out, int out_size, void* d_ws, size_t ws_size,
                              hipStream_t stream) {
    const int*   tokens = (const int*)  d_in[0];
    const float* emb    = (const float*)d_in[1];
    const float* W_ih0  = (const float*)d_in[2];
    const float* W_hh0  = (const float*)d_in[3];
    const float* b_ih0  = (const float*)d_in[4];
    const float* b_hh0  = (const float*)d_in[5];
    const float* W_ih1  = (const float*)d_in[6];
    const float* W_hh1  = (const float*)d_in[7];
    const float* b_ih1  = (const float*)d_in[8];
    const float* b_hh1  = (const float*)d_in[9];
    const float* W_out  = (const float*)d_in[10];
    const float* b_out  = (const float*)d_in[11];
    float* out = (float*)d_out;

    char* ws = (char*)d_ws;
    _Float16* wimg = (_Float16*)(ws + WIMG_B);
    float* PROJ = (float*)(ws + PROJ_B);

    // zero counters + the t=-1 ring slots (slot 3 of h0 and h1)
    hipMemsetAsync(ws + CTR0_B, 0, 4096, stream);
    hipMemsetAsync(ws + H0_B + (size_t)3 * SLOT * 2, 0, (size_t)SLOT * 2, stream);
    hipMemsetAsync(ws + H1_B + (size_t)3 * SLOT * 2, 0, (size_t)SLOT * 2, stream);

    // pack weight images (role 0: Whh0, role 1: Wih1, role 2: Whh1)
    pack_w<<<512, 256, 0, stream>>>(W_hh0, wimg);
    pack_w<<<512, 256, 0, stream>>>(W_ih1, wimg + (size_t)32 * 65536);
    pack_w<<<512, 256, 0, stream>>>(W_hh1, wimg + (size_t)64 * 65536);
    // fused input projection table (exact f32)
    proj_k<<<512, 256, 0, stream>>>(emb, W_ih0, b_ih0, PROJ);

    // persistent pipelined RNN (192 blocks, 1/CU, relaxed-flag synced)
    rnn_run<<<192, 256, 0, stream>>>(tokens, b_hh0, b_ih1, b_hh1, ws);

    // head from h1[255] (ring slot 3)
    head2<<<128, 256, 0, stream>>>((const _Float16*)(ws + H1_B) + (size_t)3 * SLOT,
                                   W_out, b_out, out);
}

// Round 6
// 6141.953 us; speedup vs baseline: 1.4042x; 1.0200x over previous
//
#include <hip/hip_runtime.h>

typedef _Float16 f16x8 __attribute__((ext_vector_type(8)));
typedef float f32x4 __attribute__((ext_vector_type(4)));

#define VOCAB 128
#define EMB 512
#define HID 1024
#define BATCH 256
#define TSEQ 256
#define SLOT (BATCH * HID)

// ---- workspace byte offsets ----
#define CTR0_B 0                                  // 256 u32
#define CTRG_B 1024
#define CTR1_B 2048
#define H0_B   4096                               // 4 slots * SLOT * 2B
#define H1_B   (H0_B + 4 * SLOT * 2)
#define PRE1_B (H1_B + 4 * SLOT * 2)              // 4 slots * SLOT * 4B
#define PROJ_B (PRE1_B + 4 * SLOT * 4)            // 128*1024*4
#define WIMG_B (PROJ_B + VOCAB * HID * 4)         // 3*32*65536 f16

// plain cached pipelined loads; coherence handled by per-step acquire fence
#define LOADX4(dst, p) asm volatile("global_load_dwordx4 %0, %1, off" : "=v"(dst) : "v"(p))
#define WAITV(n) do { asm volatile("s_waitcnt vmcnt(" #n ")" ::: "memory"); \
                      __builtin_amdgcn_sched_barrier(0); } while (0)

__device__ __forceinline__ f32x4 mfma16(f16x8 a, f16x8 b, f32x4 c) {
    return __builtin_amdgcn_mfma_f32_16x16x32_f16(a, b, c, 0, 0, 0);
}

__device__ __forceinline__ void spin64(unsigned int* p) {
    while (__hip_atomic_load(p, __ATOMIC_RELAXED, __HIP_MEMORY_SCOPE_AGENT) < 64u)
        __builtin_amdgcn_s_sleep(1);
}

// ---- pack one 1024x1024 f32 weight matrix into the LDS image (hi+lo f16) ----
// per col-block cb: [kc 0..31][half][nf 0..1][g16 0..3][ar 0..15][8 f16]
// in-kernel read addr = kc*2048 + half*1024 + nf*512 + lane*8 (linear in lane)
__global__ __launch_bounds__(256) void pack_w(const float* __restrict__ W,
                                              _Float16* __restrict__ img) {
    int i = blockIdx.x * 256 + threadIdx.x;
    if (i >= HID * 128) return;
    const int n = i >> 7;          // weight row (output col) 0..1023
    const int c = i & 127;         // 8-elem k-chunk
    const int cb = n >> 5;
    const int col = n & 31;
    const int nf = col >> 4, ar = col & 15;
    const int kc = c >> 2, g = c & 3;
    const float* src = W + (size_t)n * HID + c * 8;
    float4 u0 = *(const float4*)src;
    float4 u1 = *(const float4*)(src + 4);
    float uf[8] = {u0.x, u0.y, u0.z, u0.w, u1.x, u1.y, u1.z, u1.w};
    f16x8 hi, lo;
    #pragma unroll
    for (int j = 0; j < 8; ++j) {
        _Float16 h = (_Float16)uf[j];
        hi[j] = h;
        lo[j] = (_Float16)(uf[j] - (float)h);
    }
    const size_t base = (size_t)cb * 65536 + (size_t)kc * 2048 +
                        (size_t)nf * 512 + (size_t)g * 128 + (size_t)ar * 8;
    *(f16x8*)(img + base)        = hi;
    *(f16x8*)(img + base + 1024) = lo;
}

// ---- PROJ[v][n] = emb[v,:] . Wih0[n,:] + b_ih0[n]  (f32 exact) ----
__global__ __launch_bounds__(256) void proj_k(const float* __restrict__ emb,
                                              const float* __restrict__ Wih0,
                                              const float* __restrict__ b_ih0,
                                              float* __restrict__ PROJ) {
    int o = blockIdx.x * 256 + threadIdx.x;
    if (o >= VOCAB * HID) return;
    const int v = o >> 10, n = o & (HID - 1);
    const float* er = emb + (size_t)v * EMB;
    const float* wr = Wih0 + (size_t)n * EMB;
    float acc = 0.f;
    #pragma unroll 4
    for (int k = 0; k < EMB; k += 4) {
        float4 e = *(const float4*)(er + k);
        float4 w = *(const float4*)(wr + k);
        acc += e.x * w.x + e.y * w.y + e.z * w.z + e.w * w.w;
    }
    PROJ[o] = acc + b_ih0[n];
}

// ---- persistent RNN: 192 blocks (3 roles x 2 row-groups x 32 col-blocks) ----
#define ISSUE4(B0, B1, KCB) do { \
    const _Float16* q0_ = pr0 + (KCB) * 32; \
    const _Float16* q1_ = pr1 + (KCB) * 32; \
    LOADX4(B0[0], q0_);      LOADX4(B0[1], q0_ + 32); \
    LOADX4(B0[2], q0_ + 64); LOADX4(B0[3], q0_ + 96); \
    LOADX4(B1[0], q1_);      LOADX4(B1[1], q1_ + 32); \
    LOADX4(B1[2], q1_ + 64); LOADX4(B1[3], q1_ + 96); \
} while (0)

#define KC1(KC, AV0, AV1) do { \
    const _Float16* sb_ = simg + (KC) * 2048 + lane * 8; \
    f16x8 bh0_ = *(const f16x8*)sb_; \
    f16x8 bh1_ = *(const f16x8*)(sb_ + 512); \
    f16x8 bl0_ = *(const f16x8*)(sb_ + 1024); \
    f16x8 bl1_ = *(const f16x8*)(sb_ + 1536); \
    a00 = mfma16(AV0, bh0_, a00); a01 = mfma16(AV0, bh1_, a01); \
    a10 = mfma16(AV1, bh0_, a10); a11 = mfma16(AV1, bh1_, a11); \
    a00 = mfma16(AV0, bl0_, a00); a01 = mfma16(AV0, bl1_, a01); \
    a10 = mfma16(AV1, bl0_, a10); a11 = mfma16(AV1, bl1_, a11); \
} while (0)

#define KC4(KB, CB0, CB1) do { \
    KC1((KB) + 0, CB0[0], CB1[0]); \
    KC1((KB) + 1, CB0[1], CB1[1]); \
    KC1((KB) + 2, CB0[2], CB1[2]); \
    KC1((KB) + 3, CB0[3], CB1[3]); \
} while (0)

__global__ __launch_bounds__(256, 1) void rnn_run(
    const int* __restrict__ tokens,
    const float* __restrict__ b_hh0, const float* __restrict__ b_ih1,
    const float* __restrict__ b_hh1, char* __restrict__ ws)
{
    __shared__ _Float16 simg[65536];   // 128 KB weight slice (hi+lo)

    unsigned int* ctr0 = (unsigned int*)(ws + CTR0_B);
    unsigned int* ctrG = (unsigned int*)(ws + CTRG_B);
    unsigned int* ctr1 = (unsigned int*)(ws + CTR1_B);
    _Float16* h0 = (_Float16*)(ws + H0_B);
    _Float16* h1 = (_Float16*)(ws + H1_B);
    float* pre1 = (float*)(ws + PRE1_B);
    const float* PROJ = (const float*)(ws + PROJ_B);
    const _Float16* wimg = (const _Float16*)(ws + WIMG_B);

    const int tid = threadIdx.x, lane = tid & 63, wv = tid >> 6;
    const int blk = blockIdx.x;
    const int role = blk >> 6;           // 0,1,2
    const int sub = blk & 63;
    const int cb = sub & 31, rg = sub >> 5;
    const int n0 = cb * 32;

    // stage weight slice into LDS
    {
        const _Float16* gi = wimg + (size_t)(role * 32 + cb) * 65536;
        for (int i = tid; i < 8192; i += 256)
            *(f16x8*)&simg[(size_t)i * 8] = *(const f16x8*)&gi[(size_t)i * 8];
    }
    __syncthreads();

    const int ar = lane & 15;
    const int g16 = lane >> 4;
    const int rbase = rg * 128 + wv * 32;
    const int er0 = rbase + g16 * 4;

    const float* bias = (role == 0) ? b_hh0 : (role == 1) ? b_ih1 : b_hh1;
    const float b0 = bias[n0 + ar];
    const float b1 = bias[n0 + 16 + ar];
    unsigned int* ctr_pub = (role == 0) ? ctr0 : (role == 1) ? ctrG : ctr1;

    for (int st = 0; st < TSEQ; ++st) {
        // ---- waits (RAW + WAR, depth-4 rings): relaxed polls, then ONE
        //      acquire fence (single buffer_inv of L1 + this XCD's L2) ----
        if (tid == 0) {
            if (role == 0) {
                if (st)      spin64(ctr0 + st - 1);
                if (st >= 4) spin64(ctrG + st - 4);
            } else if (role == 1) {
                spin64(ctr0 + st);
                if (st >= 4) spin64(ctr1 + st - 4);
            } else {
                spin64(ctrG + st);
                if (st)      spin64(ctr1 + st - 1);
            }
            (void)__hip_atomic_load(ctr0 + st, __ATOMIC_ACQUIRE,
                                    __HIP_MEMORY_SCOPE_AGENT);
        }
        __syncthreads();

        const _Float16* A = (role == 0) ? h0 + (size_t)((st + 3) & 3) * SLOT
                          : (role == 1) ? h0 + (size_t)(st & 3) * SLOT
                                        : h1 + (size_t)((st + 3) & 3) * SLOT;
        const _Float16* pr0 = A + (size_t)(rbase + ar) * HID + g16 * 8;
        const _Float16* pr1 = pr0 + 16 * HID;

        f32x4 a00 = {}, a01 = {}, a10 = {}, a11 = {};
        f16x8 ca0[4], ca1[4], cb0[4], cb1[4];

        __builtin_amdgcn_sched_barrier(0);
        ISSUE4(ca0, ca1, 0);
        #pragma unroll
        for (int k8 = 0; k8 < 4; ++k8) {
            const int kb = k8 * 8;
            ISSUE4(cb0, cb1, kb + 4);
            WAITV(8);
            KC4(kb, ca0, ca1);
            if (k8 < 3) {
                ISSUE4(ca0, ca1, kb + 8);
                WAITV(8);
            } else {
                WAITV(0);
            }
            KC4(kb + 4, cb0, cb1);
        }
        __builtin_amdgcn_sched_barrier(0);

        // ---- epilogue (plain cached stores; release publishes them) ----
        if (role == 0) {
            _Float16* O = h0 + (size_t)(st & 3) * SLOT;
            #pragma unroll
            for (int mf = 0; mf < 2; ++mf) {
                #pragma unroll
                for (int r = 0; r < 4; ++r) {
                    const int rr = er0 + mf * 16 + r;
                    const int tok = tokens[rr * TSEQ + st];
                    const float* pr = PROJ + (size_t)tok * HID + n0;
                    const float v0 = (mf ? a10[r] : a00[r]) + pr[ar] + b0;
                    const float v1 = (mf ? a11[r] : a01[r]) + pr[16 + ar] + b1;
                    O[(size_t)rr * HID + n0 + ar]      = (_Float16)tanhf(v0);
                    O[(size_t)rr * HID + n0 + 16 + ar] = (_Float16)tanhf(v1);
                }
            }
        } else if (role == 1) {
            float* O = pre1 + (size_t)(st & 3) * SLOT;
            #pragma unroll
            for (int mf = 0; mf < 2; ++mf) {
                #pragma unroll
                for (int r = 0; r < 4; ++r) {
                    const int rr = er0 + mf * 16 + r;
                    O[(size_t)rr * HID + n0 + ar]      = (mf ? a10[r] : a00[r]) + b0;
                    O[(size_t)rr * HID + n0 + 16 + ar] = (mf ? a11[r] : a01[r]) + b1;
                }
            }
        } else {
            const float* P = pre1 + (size_t)(st & 3) * SLOT;
            _Float16* O = h1 + (size_t)(st & 3) * SLOT;
            #pragma unroll
            for (int mf = 0; mf < 2; ++mf) {
                #pragma unroll
                for (int r = 0; r < 4; ++r) {
                    const int rr = er0 + mf * 16 + r;
                    const size_t o0 = (size_t)rr * HID + n0 + ar;
                    const size_t o1 = o0 + 16;
                    const float v0 = (mf ? a10[r] : a00[r]) + P[o0] + b0;
                    const float v1 = (mf ? a11[r] : a01[r]) + P[o1] + b1;
                    O[o0] = (_Float16)tanhf(v0);
                    O[o1] = (_Float16)tanhf(v1);
                }
            }
        }

        __syncthreads();   // emits s_waitcnt vmcnt(0) before barrier -> stores drained
        if (tid == 0)
            __hip_atomic_fetch_add(ctr_pub + st, 1u, __ATOMIC_RELEASE,
                                   __HIP_MEMORY_SCOPE_AGENT);   // buffer_wbl2 + add
    }
}

// ---- head: out[m][n] = h1[255][m,:] . Wout[n,:] + b_out[n] ----
__global__ __launch_bounds__(256) void head2(const _Float16* __restrict__ h1last,
                                             const float* __restrict__ Wout,
                                             const float* __restrict__ b_out,
                                             float* __restrict__ out) {
    const int idx = blockIdx.x * 256 + threadIdx.x;   // 32768
    const int m = idx >> 7, n = idx & 127;
    const _Float16* hr = h1last + (size_t)m * HID;
    const float* wr = Wout + (size_t)n * HID;
    float acc = 0.f;
    #pragma unroll 4
    for (int k = 0; k < HID; k += 8) {
        f16x8 hv = *(const f16x8*)(hr + k);
        float4 w0 = *(const float4*)(wr + k);
        float4 w1 = *(const float4*)(wr + k + 4);
        acc += (float)hv[0] * w0.x + (float)hv[1] * w0.y +
               (float)hv[2] * w0.z + (float)hv[3] * w0.w +
               (float)hv[4] * w1.x + (float)hv[5] * w1.y +
               (float)hv[6] * w1.z + (float)hv[7] * w1.w;
    }
    out[idx] = acc + b_out[n];
}

extern "C" void kernel_launch(void* const* d_in, const int* in_sizes, int n_in,
                              void* d_out, int out_size, void* d_ws, size_t ws_size,
                              hipStream_t stream) {
    const int*   tokens = (const int*)  d_in[0];
    const float* emb    = (const float*)d_in[1];
    const float* W_ih0  = (const float*)d_in[2];
    const float* W_hh0  = (const float*)d_in[3];
    const float* b_ih0  = (const float*)d_in[4];
    const float* b_hh0  = (const float*)d_in[5];
    const float* W_ih1  = (const float*)d_in[6];
    const float* W_hh1  = (const float*)d_in[7];
    const float* b_ih1  = (const float*)d_in[8];
    const float* b_hh1  = (const float*)d_in[9];
    const float* W_out  = (const float*)d_in[10];
    const float* b_out  = (const float*)d_in[11];
    float* out = (float*)d_out;

    char* ws = (char*)d_ws;
    _Float16* wimg = (_Float16*)(ws + WIMG_B);
    float* PROJ = (float*)(ws + PROJ_B);

    // zero counters + the t=-1 ring slots (slot 3 of h0 and h1)
    hipMemsetAsync(ws + CTR0_B, 0, 4096, stream);
    hipMemsetAsync(ws + H0_B + (size_t)3 * SLOT * 2, 0, (size_t)SLOT * 2, stream);
    hipMemsetAsync(ws + H1_B + (size_t)3 * SLOT * 2, 0, (size_t)SLOT * 2, stream);

    // pack weight images (role 0: Whh0, role 1: Wih1, role 2: Whh1)
    pack_w<<<512, 256, 0, stream>>>(W_hh0, wimg);
    pack_w<<<512, 256, 0, stream>>>(W_ih1, wimg + (size_t)32 * 65536);
    pack_w<<<512, 256, 0, stream>>>(W_hh1, wimg + (size_t)64 * 65536);
    // fused input projection table (exact f32)
    proj_k<<<512, 256, 0, stream>>>(emb, W_ih0, b_ih0, PROJ);

    // persistent pipelined RNN (192 blocks, 1/CU, relaxed-flag synced)
    rnn_run<<<192, 256, 0, stream>>>(tokens, b_hh0, b_ih1, b_hh1, ws);

    // head from h1[255] (ring slot 3)
    head2<<<128, 256, 0, stream>>>((const _Float16*)(ws + H1_B) + (size_t)3 * SLOT,
                                   W_out, b_out, out);
}

// Round 8
// 4305.198 us; speedup vs baseline: 2.0033x; 1.4266x over previous
//
#include <hip/hip_runtime.h>

typedef _Float16 f16x8 __attribute__((ext_vector_type(8)));
typedef float f32x4 __attribute__((ext_vector_type(4)));

#define VOCAB 128
#define EMB 512
#define HID 1024
#define BATCH 256
#define TSEQ 256
#define SLOT (BATCH * HID)

// ---- workspace byte offsets ----
#define CTR0_B 0                                  // 256 u32
#define CTRG_B 1024
#define CTR1_B 2048
#define H0_B   4096                               // 4 slots * SLOT * 2B
#define H1_B   (H0_B + 4 * SLOT * 2)
#define PRE1_B (H1_B + 4 * SLOT * 2)              // 4 slots * SLOT * 4B
#define PROJ_B (PRE1_B + 4 * SLOT * 4)            // 128*1024*4
#define WIMG_B (PROJ_B + VOCAB * HID * 4)         // 3*32*65536 f16

// cached pipelined loads (freshness via one acquire-inv per step)
#define LOADX4(dst, p) asm volatile("global_load_dwordx4 %0, %1, off" : "=v"(dst) : "v"(p))
// write-through device-coherent vector store (lands at LLC, leaves no dirty L2)
#define STOREX4(p, v)  asm volatile("global_store_dwordx4 %0, %1, off sc0 sc1" :: "v"(p), "v"(v) : "memory")
#define WAITV(n) do { asm volatile("s_waitcnt vmcnt(" #n ")" ::: "memory"); \
                      __builtin_amdgcn_sched_barrier(0); } while (0)

__device__ __forceinline__ f32x4 mfma16(f16x8 a, f16x8 b, f32x4 c) {
    return __builtin_amdgcn_mfma_f32_16x16x32_f16(a, b, c, 0, 0, 0);
}

__device__ __forceinline__ void spin64(unsigned int* p) {
    while (__hip_atomic_load(p, __ATOMIC_RELAXED, __HIP_MEMORY_SCOPE_AGENT) < 64u)
        __builtin_amdgcn_s_sleep(1);
}

// ---- pack one 1024x1024 f32 weight matrix into the LDS image (hi+lo f16) ----
// per col-block cb: [kc 0..31][half][nf 0..1][g16 0..3][ar 0..15][8 f16]
__global__ __launch_bounds__(256) void pack_w(const float* __restrict__ W,
                                              _Float16* __restrict__ img) {
    int i = blockIdx.x * 256 + threadIdx.x;
    if (i >= HID * 128) return;
    const int n = i >> 7;
    const int c = i & 127;
    const int cb = n >> 5;
    const int col = n & 31;
    const int nf = col >> 4, ar = col & 15;
    const int kc = c >> 2, g = c & 3;
    const float* src = W + (size_t)n * HID + c * 8;
    float4 u0 = *(const float4*)src;
    float4 u1 = *(const float4*)(src + 4);
    float uf[8] = {u0.x, u0.y, u0.z, u0.w, u1.x, u1.y, u1.z, u1.w};
    f16x8 hi, lo;
    #pragma unroll
    for (int j = 0; j < 8; ++j) {
        _Float16 h = (_Float16)uf[j];
        hi[j] = h;
        lo[j] = (_Float16)(uf[j] - (float)h);
    }
    const size_t base = (size_t)cb * 65536 + (size_t)kc * 2048 +
                        (size_t)nf * 512 + (size_t)g * 128 + (size_t)ar * 8;
    *(f16x8*)(img + base)        = hi;
    *(f16x8*)(img + base + 1024) = lo;
}

// ---- PROJ[v][n] = emb[v,:] . Wih0[n,:] + b_ih0[n]  (f32 exact) ----
__global__ __launch_bounds__(256) void proj_k(const float* __restrict__ emb,
                                              const float* __restrict__ Wih0,
                                              const float* __restrict__ b_ih0,
                                              float* __restrict__ PROJ) {
    int o = blockIdx.x * 256 + threadIdx.x;
    if (o >= VOCAB * HID) return;
    const int v = o >> 10, n = o & (HID - 1);
    const float* er = emb + (size_t)v * EMB;
    const float* wr = Wih0 + (size_t)n * EMB;
    float acc = 0.f;
    #pragma unroll 4
    for (int k = 0; k < EMB; k += 4) {
        float4 e = *(const float4*)(er + k);
        float4 w = *(const float4*)(wr + k);
        acc += e.x * w.x + e.y * w.y + e.z * w.z + e.w * w.w;
    }
    PROJ[o] = acc + b_ih0[n];
}

// ---- persistent RNN: 192 blocks (3 roles x 2 row-groups x 32 col-blocks) ----
#define ISSUE4(B0, B1, KCB) do { \
    const _Float16* q0_ = pr0 + (KCB) * 32; \
    const _Float16* q1_ = pr1 + (KCB) * 32; \
    LOADX4(B0[0], q0_);      LOADX4(B0[1], q0_ + 32); \
    LOADX4(B0[2], q0_ + 64); LOADX4(B0[3], q0_ + 96); \
    LOADX4(B1[0], q1_);      LOADX4(B1[1], q1_ + 32); \
    LOADX4(B1[2], q1_ + 64); LOADX4(B1[3], q1_ + 96); \
} while (0)

#define KC1(KC, AV0, AV1) do { \
    const _Float16* sb_ = simg + (KC) * 2048 + lane * 8; \
    f16x8 bh0_ = *(const f16x8*)sb_; \
    f16x8 bh1_ = *(const f16x8*)(sb_ + 512); \
    f16x8 bl0_ = *(const f16x8*)(sb_ + 1024); \
    f16x8 bl1_ = *(const f16x8*)(sb_ + 1536); \
    a00 = mfma16(AV0, bh0_, a00); a01 = mfma16(AV0, bh1_, a01); \
    a10 = mfma16(AV1, bh0_, a10); a11 = mfma16(AV1, bh1_, a11); \
    a00 = mfma16(AV0, bl0_, a00); a01 = mfma16(AV0, bl1_, a01); \
    a10 = mfma16(AV1, bl0_, a10); a11 = mfma16(AV1, bl1_, a11); \
} while (0)

#define KC4(KB, CB0, CB1) do { \
    KC1((KB) + 0, CB0[0], CB1[0]); \
    KC1((KB) + 1, CB0[1], CB1[1]); \
    KC1((KB) + 2, CB0[2], CB1[2]); \
    KC1((KB) + 3, CB0[3], CB1[3]); \
} while (0)

__global__ __launch_bounds__(256, 1) void rnn_run(
    const int* __restrict__ tokens,
    const float* __restrict__ b_hh0, const float* __restrict__ b_ih1,
    const float* __restrict__ b_hh1, char* __restrict__ ws)
{
    __shared__ _Float16 simg[65536];                 // 128 KB weight slice
    __shared__ __align__(16) char stageb[4][4096];   // 16 KB per-wave output staging

    unsigned int* ctr0 = (unsigned int*)(ws + CTR0_B);
    unsigned int* ctrG = (unsigned int*)(ws + CTRG_B);
    unsigned int* ctr1 = (unsigned int*)(ws + CTR1_B);
    _Float16* h0 = (_Float16*)(ws + H0_B);
    _Float16* h1 = (_Float16*)(ws + H1_B);
    float* pre1 = (float*)(ws + PRE1_B);
    const float* PROJ = (const float*)(ws + PROJ_B);
    const _Float16* wimg = (const _Float16*)(ws + WIMG_B);

    const int tid = threadIdx.x, lane = tid & 63, wv = tid >> 6;
    const int blk = blockIdx.x;
    const int role = blk >> 6;
    const int sub = blk & 63;
    const int cb = sub & 31, rg = sub >> 5;
    const int n0 = cb * 32;

    // stage weight slice into LDS
    {
        const _Float16* gi = wimg + (size_t)(role * 32 + cb) * 65536;
        for (int i = tid; i < 8192; i += 256)
            *(f16x8*)&simg[(size_t)i * 8] = *(const f16x8*)&gi[(size_t)i * 8];
    }
    __syncthreads();

    const int ar = lane & 15;
    const int g16 = lane >> 4;
    const int rbase = rg * 128 + wv * 32;
    const int er0 = rbase + g16 * 4;

    const float* bias = (role == 0) ? b_hh0 : (role == 1) ? b_ih1 : b_hh1;
    const float b0 = bias[n0 + ar];
    const float b1 = bias[n0 + 16 + ar];
    unsigned int* ctr_pub = (role == 0) ? ctr0 : (role == 1) ? ctrG : ctr1;

    for (int st = 0; st < TSEQ; ++st) {
        // ---- waits: relaxed polls, then ONE acquire fence (single inv) ----
        if (tid == 0) {
            if (role == 0) {
                if (st)      spin64(ctr0 + st - 1);
                if (st >= 4) spin64(ctrG + st - 4);
            } else if (role == 1) {
                spin64(ctr0 + st);
                if (st >= 4) spin64(ctr1 + st - 4);
            } else {
                spin64(ctrG + st);
                if (st)      spin64(ctr1 + st - 1);
            }
            (void)__hip_atomic_load(ctr0 + st, __ATOMIC_ACQUIRE,
                                    __HIP_MEMORY_SCOPE_AGENT);
        }
        __syncthreads();

        const _Float16* A = (role == 0) ? h0 + (size_t)((st + 3) & 3) * SLOT
                          : (role == 1) ? h0 + (size_t)(st & 3) * SLOT
                                        : h1 + (size_t)((st + 3) & 3) * SLOT;
        const _Float16* pr0 = A + (size_t)(rbase + ar) * HID + g16 * 8;
        const _Float16* pr1 = pr0 + 16 * HID;

        f32x4 a00 = {}, a01 = {}, a10 = {}, a11 = {};
        f16x8 ca0[4], ca1[4], cb0[4], cb1[4];

        __builtin_amdgcn_sched_barrier(0);
        ISSUE4(ca0, ca1, 0);
        #pragma unroll
        for (int k8 = 0; k8 < 4; ++k8) {
            const int kb = k8 * 8;
            ISSUE4(cb0, cb1, kb + 4);
            WAITV(8);
            KC4(kb, ca0, ca1);
            if (k8 < 3) {
                ISSUE4(ca0, ca1, kb + 8);
                WAITV(8);
            } else {
                WAITV(0);
            }
            KC4(kb + 4, cb0, cb1);
        }
        __builtin_amdgcn_sched_barrier(0);

        // ---- epilogue: stage tile in LDS, then vector write-through stores ----
        if (role == 0) {
            _Float16* sg = (_Float16*)stageb[wv];
            _Float16* O = h0 + (size_t)(st & 3) * SLOT;
            #pragma unroll
            for (int mf = 0; mf < 2; ++mf) {
                #pragma unroll
                for (int r = 0; r < 4; ++r) {
                    const int rr = er0 + mf * 16 + r;
                    const int trow = g16 * 4 + mf * 16 + r;
                    const int tok = tokens[rr * TSEQ + st];
                    const float* pr = PROJ + (size_t)tok * HID + n0;
                    const float v0 = (mf ? a10[r] : a00[r]) + pr[ar] + b0;
                    const float v1 = (mf ? a11[r] : a01[r]) + pr[16 + ar] + b1;
                    sg[trow * 32 + ar]      = (_Float16)tanhf(v0);
                    sg[trow * 32 + 16 + ar] = (_Float16)tanhf(v1);
                }
            }
            __syncthreads();
            #pragma unroll
            for (int j = 0; j < 2; ++j) {
                const int trow = j * 16 + (lane >> 2);
                f32x4 sv = *(const f32x4*)((const char*)sg + trow * 64 + (lane & 3) * 16);
                STOREX4(O + (size_t)(rbase + trow) * HID + n0 + (lane & 3) * 8, sv);
            }
        } else if (role == 1) {
            float* sg = (float*)stageb[wv];
            float* O = pre1 + (size_t)(st & 3) * SLOT;
            #pragma unroll
            for (int mf = 0; mf < 2; ++mf) {
                #pragma unroll
                for (int r = 0; r < 4; ++r) {
                    const int trow = g16 * 4 + mf * 16 + r;
                    sg[trow * 32 + ar]      = (mf ? a10[r] : a00[r]) + b0;
                    sg[trow * 32 + 16 + ar] = (mf ? a11[r] : a01[r]) + b1;
                }
            }
            __syncthreads();
            #pragma unroll
            for (int i = 0; i < 4; ++i) {
                const int trow = i * 8 + (lane >> 3);
                f32x4 sv = *(const f32x4*)((const char*)sg + trow * 128 + (lane & 7) * 16);
                STOREX4(O + (size_t)(rbase + trow) * HID + n0 + (lane & 7) * 4, sv);
            }
        } else {
            const float* P = pre1 + (size_t)(st & 3) * SLOT;
            _Float16* sg = (_Float16*)stageb[wv];
            _Float16* O = h1 + (size_t)(st & 3) * SLOT;
            #pragma unroll
            for (int mf = 0; mf < 2; ++mf) {
                #pragma unroll
                for (int r = 0; r < 4; ++r) {
                    const int rr = er0 + mf * 16 + r;
                    const int trow = g16 * 4 + mf * 16 + r;
                    const size_t o0 = (size_t)rr * HID + n0 + ar;
                    const float v0 = (mf ? a10[r] : a00[r]) + P[o0] + b0;
                    const float v1 = (mf ? a11[r] : a01[r]) + P[o0 + 16] + b1;
                    sg[trow * 32 + ar]      = (_Float16)tanhf(v0);
                    sg[trow * 32 + 16 + ar] = (_Float16)tanhf(v1);
                }
            }
            __syncthreads();
            #pragma unroll
            for (int j = 0; j < 2; ++j) {
                const int trow = j * 16 + (lane >> 2);
                f32x4 sv = *(const f32x4*)((const char*)sg + trow * 64 + (lane & 3) * 16);
                STOREX4(O + (size_t)(rbase + trow) * HID + n0 + (lane & 3) * 8, sv);
            }
        }

        // stores are write-through; vmcnt(0) drain = visible at LLC
        asm volatile("s_waitcnt vmcnt(0)" ::: "memory");
        __syncthreads();
        if (tid == 0)
            __hip_atomic_fetch_add(ctr_pub + st, 1u, __ATOMIC_RELAXED,
                                   __HIP_MEMORY_SCOPE_AGENT);   // no wbl2
    }
}

// ---- head: out[m][n] = h1[255][m,:] . Wout[n,:] + b_out[n] ----
__global__ __launch_bounds__(256) void head2(const _Float16* __restrict__ h1last,
                                             const float* __restrict__ Wout,
                                             const float* __restrict__ b_out,
                                             float* __restrict__ out) {
    const int idx = blockIdx.x * 256 + threadIdx.x;
    const int m = idx >> 7, n = idx & 127;
    const _Float16* hr = h1last + (size_t)m * HID;
    const float* wr = Wout + (size_t)n * HID;
    float acc = 0.f;
    #pragma unroll 4
    for (int k = 0; k < HID; k += 8) {
        f16x8 hv = *(const f16x8*)(hr + k);
        float4 w0 = *(const float4*)(wr + k);
        float4 w1 = *(const float4*)(wr + k + 4);
        acc += (float)hv[0] * w0.x + (float)hv[1] * w0.y +
               (float)hv[2] * w0.z + (float)hv[3] * w0.w +
               (float)hv[4] * w1.x + (float)hv[5] * w1.y +
               (float)hv[6] * w1.z + (float)hv[7] * w1.w;
    }
    out[idx] = acc + b_out[n];
}

extern "C" void kernel_launch(void* const* d_in, const int* in_sizes, int n_in,
                              void* d_out, int out_size, void* d_ws, size_t ws_size,
                              hipStream_t stream) {
    const int*   tokens = (const int*)  d_in[0];
    const float* emb    = (const float*)d_in[1];
    const float* W_ih0  = (const float*)d_in[2];
    const float* W_hh0  = (const float*)d_in[3];
    const float* b_ih0  = (const float*)d_in[4];
    const float* b_hh0  = (const float*)d_in[5];
    const float* W_ih1  = (const float*)d_in[6];
    const float* W_hh1  = (const float*)d_in[7];
    const float* b_ih1  = (const float*)d_in[8];
    const float* b_hh1  = (const float*)d_in[9];
    const float* W_out  = (const float*)d_in[10];
    const float* b_out  = (const float*)d_in[11];
    float* out = (float*)d_out;

    char* ws = (char*)d_ws;
    _Float16* wimg = (_Float16*)(ws + WIMG_B);
    float* PROJ = (float*)(ws + PROJ_B);

    // zero counters + the t=-1 ring slots (slot 3 of h0 and h1)
    (void)hipMemsetAsync(ws + CTR0_B, 0, 4096, stream);
    (void)hipMemsetAsync(ws + H0_B + (size_t)3 * SLOT * 2, 0, (size_t)SLOT * 2, stream);
    (void)hipMemsetAsync(ws + H1_B + (size_t)3 * SLOT * 2, 0, (size_t)SLOT * 2, stream);

    // pack weight images (role 0: Whh0, role 1: Wih1, role 2: Whh1)
    pack_w<<<512, 256, 0, stream>>>(W_hh0, wimg);
    pack_w<<<512, 256, 0, stream>>>(W_ih1, wimg + (size_t)32 * 65536);
    pack_w<<<512, 256, 0, stream>>>(W_hh1, wimg + (size_t)64 * 65536);
    // fused input projection table (exact f32)
    proj_k<<<512, 256, 0, stream>>>(emb, W_ih0, b_ih0, PROJ);

    // persistent pipelined RNN (192 blocks, 1/CU, relaxed-flag synced)
    rnn_run<<<192, 256, 0, stream>>>(tokens, b_hh0, b_ih1, b_hh1, ws);

    // head from h1[255] (ring slot 3)
    head2<<<128, 256, 0, stream>>>((const _Float16*)(ws + H1_B) + (size_t)3 * SLOT,
                                   W_out, b_out, out);
}

// Round 9
// 4287.240 us; speedup vs baseline: 2.0117x; 1.0042x over previous
//
#include <hip/hip_runtime.h>

typedef _Float16 f16x8 __attribute__((ext_vector_type(8)));
typedef float f32x4 __attribute__((ext_vector_type(4)));

#define VOCAB 128
#define EMB 512
#define HID 1024
#define BATCH 256
#define TSEQ 256
#define SLOT (BATCH * HID)

// ---- workspace byte offsets ----
#define FLG0_B 0                                  // 64 u32 (one per role-0 block)
#define FLGG_B 1024
#define FLG1_B 2048
#define H0_B   4096                               // 4 slots * SLOT * 2B
#define H1_B   (H0_B + 4 * SLOT * 2)
#define PRE1_B (H1_B + 4 * SLOT * 2)              // 4 slots * SLOT * 4B
#define PROJ_B (PRE1_B + 4 * SLOT * 4)            // 128*1024*4
#define WIMG_B (PROJ_B + VOCAB * HID * 4)         // 3*32*65536 f16

// cached pipelined loads (freshness via one acquire-inv per step)
#define LOADX4(dst, p) asm volatile("global_load_dwordx4 %0, %1, off" : "=v"(dst) : "v"(p))
// device-coherent (LLC) ops for ring stores and flags
#define STOREX4(p, v)  asm volatile("global_store_dwordx4 %0, %1, off sc0 sc1" :: "v"(p), "v"(v) : "memory")
#define STOREU(p, v)   asm volatile("global_store_dword %0, %1, off sc0 sc1" :: "v"(p), "v"(v) : "memory")
#define LOADU(dst, p)  asm volatile("global_load_dword %0, %1, off sc0 sc1" : "=v"(dst) : "v"(p))
#define WAITV(n) do { asm volatile("s_waitcnt vmcnt(" #n ")" ::: "memory"); \
                      __builtin_amdgcn_sched_barrier(0); } while (0)

__device__ __forceinline__ f32x4 mfma16(f16x8 a, f16x8 b, f32x4 c) {
    return __builtin_amdgcn_mfma_f32_16x16x32_f16(a, b, c, 0, 0, 0);
}

// wave-parallel flag wait: lane i polls flags[i] (64 flags), all must reach target
__device__ __forceinline__ void wait_flags(const unsigned int* f, int target, int lane) {
    if (target <= 0) return;
    const unsigned int* p = f + lane;
    while (true) {
        unsigned int v;
        LOADU(v, p);
        WAITV(0);
        if (__all((int)v >= target)) break;
        __builtin_amdgcn_s_sleep(2);
    }
}

// ---- pack one 1024x1024 f32 weight matrix into the LDS image (hi+lo f16) ----
// per col-block cb: [kc 0..31][half][nf 0..1][g16 0..3][ar 0..15][8 f16]
__global__ __launch_bounds__(256) void pack_w(const float* __restrict__ W,
                                              _Float16* __restrict__ img) {
    int i = blockIdx.x * 256 + threadIdx.x;
    if (i >= HID * 128) return;
    const int n = i >> 7;
    const int c = i & 127;
    const int cb = n >> 5;
    const int col = n & 31;
    const int nf = col >> 4, ar = col & 15;
    const int kc = c >> 2, g = c & 3;
    const float* src = W + (size_t)n * HID + c * 8;
    float4 u0 = *(const float4*)src;
    float4 u1 = *(const float4*)(src + 4);
    float uf[8] = {u0.x, u0.y, u0.z, u0.w, u1.x, u1.y, u1.z, u1.w};
    f16x8 hi, lo;
    #pragma unroll
    for (int j = 0; j < 8; ++j) {
        _Float16 h = (_Float16)uf[j];
        hi[j] = h;
        lo[j] = (_Float16)(uf[j] - (float)h);
    }
    const size_t base = (size_t)cb * 65536 + (size_t)kc * 2048 +
                        (size_t)nf * 512 + (size_t)g * 128 + (size_t)ar * 8;
    *(f16x8*)(img + base)        = hi;
    *(f16x8*)(img + base + 1024) = lo;
}

// ---- PROJ[v][n] = emb[v,:] . Wih0[n,:] + b_ih0[n]  (f32 exact) ----
__global__ __launch_bounds__(256) void proj_k(const float* __restrict__ emb,
                                              const float* __restrict__ Wih0,
                                              const float* __restrict__ b_ih0,
                                              float* __restrict__ PROJ) {
    int o = blockIdx.x * 256 + threadIdx.x;
    if (o >= VOCAB * HID) return;
    const int v = o >> 10, n = o & (HID - 1);
    const float* er = emb + (size_t)v * EMB;
    const float* wr = Wih0 + (size_t)n * EMB;
    float acc = 0.f;
    #pragma unroll 4
    for (int k = 0; k < EMB; k += 4) {
        float4 e = *(const float4*)(er + k);
        float4 w = *(const float4*)(wr + k);
        acc += e.x * w.x + e.y * w.y + e.z * w.z + e.w * w.w;
    }
    PROJ[o] = acc + b_ih0[n];
}

// ---- persistent RNN: 192 blocks x 512 threads ----
// block: role (0:R0 1:G1 2:R1) x rg (128 rows) x cb (32 cols)
// wave:  kh = wv>>2 (K half), cwv = wv&3 (32-row subtile); k-split pairs share a tile.
#define ISSUE4(B0, B1, KCB) do { \
    const _Float16* q0_ = pr0 + (KCB) * 32; \
    const _Float16* q1_ = pr1 + (KCB) * 32; \
    LOADX4(B0[0], q0_);      LOADX4(B0[1], q0_ + 32); \
    LOADX4(B0[2], q0_ + 64); LOADX4(B0[3], q0_ + 96); \
    LOADX4(B1[0], q1_);      LOADX4(B1[1], q1_ + 32); \
    LOADX4(B1[2], q1_ + 64); LOADX4(B1[3], q1_ + 96); \
} while (0)

#define KC1(KC, AV0, AV1) do { \
    const _Float16* sb_ = simgk + (KC) * 2048 + lane * 8; \
    f16x8 bh0_ = *(const f16x8*)sb_; \
    f16x8 bh1_ = *(const f16x8*)(sb_ + 512); \
    f16x8 bl0_ = *(const f16x8*)(sb_ + 1024); \
    f16x8 bl1_ = *(const f16x8*)(sb_ + 1536); \
    a00 = mfma16(AV0, bh0_, a00); a01 = mfma16(AV0, bh1_, a01); \
    a10 = mfma16(AV1, bh0_, a10); a11 = mfma16(AV1, bh1_, a11); \
    a00 = mfma16(AV0, bl0_, a00); a01 = mfma16(AV0, bl1_, a01); \
    a10 = mfma16(AV1, bl0_, a10); a11 = mfma16(AV1, bl1_, a11); \
} while (0)

#define KC4(KB, CB0, CB1) do { \
    KC1((KB) + 0, CB0[0], CB1[0]); \
    KC1((KB) + 1, CB0[1], CB1[1]); \
    KC1((KB) + 2, CB0[2], CB1[2]); \
    KC1((KB) + 3, CB0[3], CB1[3]); \
} while (0)

__global__ __launch_bounds__(512, 1) void rnn_run(
    const int* __restrict__ tokens,
    const float* __restrict__ b_hh0, const float* __restrict__ b_ih1,
    const float* __restrict__ b_hh1, char* __restrict__ ws)
{
    __shared__ _Float16 simg[65536];                 // 128 KB weight slice (hi+lo)
    __shared__ __align__(16) char stageraw[16896];   // partial-acc / output staging

    unsigned int* flag0 = (unsigned int*)(ws + FLG0_B);
    unsigned int* flagG = (unsigned int*)(ws + FLGG_B);
    unsigned int* flag1 = (unsigned int*)(ws + FLG1_B);
    _Float16* h0 = (_Float16*)(ws + H0_B);
    _Float16* h1 = (_Float16*)(ws + H1_B);
    float* pre1 = (float*)(ws + PRE1_B);
    const float* PROJ = (const float*)(ws + PROJ_B);
    const _Float16* wimg = (const _Float16*)(ws + WIMG_B);

    const int tid = threadIdx.x, lane = tid & 63, wv = tid >> 6;
    const int kh = wv >> 2, cwv = wv & 3;
    const int blk = blockIdx.x;
    const int role = blk >> 6;
    const int sub = blk & 63;
    const int cb = sub & 31, rg = sub >> 5;
    const int n0 = cb * 32;

    // stage weight slice into LDS (read-only path, cached)
    {
        const _Float16* gi = wimg + (size_t)(role * 32 + cb) * 65536;
        for (int i = tid; i < 8192; i += 512)
            *(f16x8*)&simg[(size_t)i * 8] = *(const f16x8*)&gi[(size_t)i * 8];
    }
    __syncthreads();

    const int ar = lane & 15;
    const int g16 = lane >> 4;
    const int rbase = rg * 128 + cwv * 32;
    const _Float16* simgk = simg + kh * 32768;       // this wave's K half of the image
    float* pst = (float*)stageraw;                   // padded partial tiles [4][32][33]

    const float* bias = (role == 0) ? b_hh0 : (role == 1) ? b_ih1 : b_hh1;
    const float b0 = bias[n0 + ar];
    const float b1 = bias[n0 + 16 + ar];
    unsigned int* flag_pub = (role == 0) ? flag0 : (role == 1) ? flagG : flag1;

    for (int st = 0; st < TSEQ; ++st) {
        // ---- waits: wave 0 polls flag arrays (plain sc loads), then one
        //      acquire fence (single buffer_inv of L1 + this XCD's L2) ----
        if (wv == 0) {
            if (role == 0) {
                wait_flags(flag0, st, lane);          // h0[st-1] ready (own role)
                wait_flags(flagG, st - 3, lane);      // WAR: G1 consumed slot
            } else if (role == 1) {
                wait_flags(flag0, st + 1, lane);      // h0[st] ready
                wait_flags(flag1, st - 3, lane);      // WAR: R1 consumed pre1 slot
            } else {
                wait_flags(flagG, st + 1, lane);      // pre1[st] ready
                wait_flags(flag1, st, lane);          // h1[st-1] ready (own role)
            }
            if (lane == 0)
                (void)__hip_atomic_load(flag0, __ATOMIC_ACQUIRE,
                                        __HIP_MEMORY_SCOPE_AGENT);
        }
        __syncthreads();

        const _Float16* A = (role == 0) ? h0 + (size_t)((st + 3) & 3) * SLOT
                          : (role == 1) ? h0 + (size_t)(st & 3) * SLOT
                                        : h1 + (size_t)((st + 3) & 3) * SLOT;
        // this wave: rows rbase..rbase+31, K half kh (k offset kh*512)
        const _Float16* pr0 = A + (size_t)(rbase + ar) * HID + kh * 512 + g16 * 8;
        const _Float16* pr1 = pr0 + 16 * HID;

        f32x4 a00 = {}, a01 = {}, a10 = {}, a11 = {};
        f16x8 ca0[4], ca1[4], cb0[4], cb1[4];

        __builtin_amdgcn_sched_barrier(0);
        ISSUE4(ca0, ca1, 0);
        ISSUE4(cb0, cb1, 4);
        WAITV(8);
        KC4(0, ca0, ca1);
        ISSUE4(ca0, ca1, 8);
        WAITV(8);
        KC4(4, cb0, cb1);
        ISSUE4(cb0, cb1, 12);
        WAITV(8);
        KC4(8, ca0, ca1);
        WAITV(0);
        KC4(12, cb0, cb1);
        __builtin_amdgcn_sched_barrier(0);

        // ---- k-split partial-acc exchange (padded stride 33 to spread banks) ----
        {
            float* t = pst + cwv * 1056;
            if (kh == 1) {
                #pragma unroll
                for (int r = 0; r < 4; ++r) {
                    t[(g16 * 4 + r) * 33 + ar]      = a00[r];
                    t[(g16 * 4 + r) * 33 + 16 + ar] = a01[r];
                }
            } else {
                #pragma unroll
                for (int r = 0; r < 4; ++r) {
                    t[(16 + g16 * 4 + r) * 33 + ar]      = a10[r];
                    t[(16 + g16 * 4 + r) * 33 + 16 + ar] = a11[r];
                }
            }
        }
        __syncthreads();
        {
            float* t = pst + cwv * 1056;
            if (kh == 0) {
                #pragma unroll
                for (int r = 0; r < 4; ++r) {
                    a00[r] += t[(g16 * 4 + r) * 33 + ar];
                    a01[r] += t[(g16 * 4 + r) * 33 + 16 + ar];
                }
            } else {
                #pragma unroll
                for (int r = 0; r < 4; ++r) {
                    a10[r] += t[(16 + g16 * 4 + r) * 33 + ar];
                    a11[r] += t[(16 + g16 * 4 + r) * 33 + 16 + ar];
                }
            }
        }
        __syncthreads();   // partial region now reusable as output stage

        // ---- epilogue: this wave owns 16 rows (kh half of the 32-row tile) ----
        f32x4& e0 = kh ? a10 : a00;                  // nf=0 cols
        f32x4& e1 = kh ? a11 : a01;                  // nf=1 cols
        const int rowb = rbase + kh * 16;            // wave's first owned row

        if (role == 0) {
            _Float16* sg = (_Float16*)(stageraw + wv * 2048);
            _Float16* O = h0 + (size_t)(st & 3) * SLOT;
            #pragma unroll
            for (int r = 0; r < 4; ++r) {
                const int erow = rowb + g16 * 4 + r;
                const int tok = tokens[erow * TSEQ + st];
                const float* pr = PROJ + (size_t)tok * HID + n0;
                sg[(g16 * 4 + r) * 32 + ar]      = (_Float16)tanhf(e0[r] + pr[ar] + b0);
                sg[(g16 * 4 + r) * 32 + 16 + ar] = (_Float16)tanhf(e1[r] + pr[16 + ar] + b1);
            }
            const int row = lane >> 2, part = lane & 3;
            f32x4 sv = *(const f32x4*)((const char*)sg + row * 64 + part * 16);
            STOREX4(O + (size_t)(rowb + row) * HID + n0 + part * 8, sv);
        } else if (role == 1) {
            float* sg = (float*)(stageraw + wv * 2048);
            float* O = pre1 + (size_t)(st & 3) * SLOT;
            #pragma unroll
            for (int r = 0; r < 4; ++r) {
                sg[(g16 * 4 + r) * 32 + ar]      = e0[r] + b0;
                sg[(g16 * 4 + r) * 32 + 16 + ar] = e1[r] + b1;
            }
            #pragma unroll
            for (int it = 0; it < 2; ++it) {
                const int row = it * 8 + (lane >> 3), part = lane & 7;
                f32x4 sv = *(const f32x4*)((const char*)sg + row * 128 + part * 16);
                STOREX4(O + (size_t)(rowb + row) * HID + n0 + part * 4, sv);
            }
        } else {
            const float* P = pre1 + (size_t)(st & 3) * SLOT;
            _Float16* sg = (_Float16*)(stageraw + wv * 2048);
            _Float16* O = h1 + (size_t)(st & 3) * SLOT;
            #pragma unroll
            for (int r = 0; r < 4; ++r) {
                const int erow = rowb + g16 * 4 + r;
                const size_t o0 = (size_t)erow * HID + n0 + ar;
                sg[(g16 * 4 + r) * 32 + ar]      = (_Float16)tanhf(e0[r] + P[o0] + b0);
                sg[(g16 * 4 + r) * 32 + 16 + ar] = (_Float16)tanhf(e1[r] + P[o0 + 16] + b1);
            }
            const int row = lane >> 2, part = lane & 3;
            f32x4 sv = *(const f32x4*)((const char*)sg + row * 64 + part * 16);
            STOREX4(O + (size_t)(rowb + row) * HID + n0 + part * 8, sv);
        }

        // drain write-through stores (at LLC once vmcnt==0), then publish
        WAITV(0);
        __syncthreads();
        if (tid == 0)
            STOREU(flag_pub + sub, (unsigned int)(st + 1));
    }
}

// ---- head: out[m][n] = h1[255][m,:] . Wout[n,:] + b_out[n] ----
__global__ __launch_bounds__(256) void head2(const _Float16* __restrict__ h1last,
                                             const float* __restrict__ Wout,
                                             const float* __restrict__ b_out,
                                             float* __restrict__ out) {
    const int idx = blockIdx.x * 256 + threadIdx.x;
    const int m = idx >> 7, n = idx & 127;
    const _Float16* hr = h1last + (size_t)m * HID;
    const float* wr = Wout + (size_t)n * HID;
    float acc = 0.f;
    #pragma unroll 4
    for (int k = 0; k < HID; k += 8) {
        f16x8 hv = *(const f16x8*)(hr + k);
        float4 w0 = *(const float4*)(wr + k);
        float4 w1 = *(const float4*)(wr + k + 4);
        acc += (float)hv[0] * w0.x + (float)hv[1] * w0.y +
               (float)hv[2] * w0.z + (float)hv[3] * w0.w +
               (float)hv[4] * w1.x + (float)hv[5] * w1.y +
               (float)hv[6] * w1.z + (float)hv[7] * w1.w;
    }
    out[idx] = acc + b_out[n];
}

extern "C" void kernel_launch(void* const* d_in, const int* in_sizes, int n_in,
                              void* d_out, int out_size, void* d_ws, size_t ws_size,
                              hipStream_t stream) {
    const int*   tokens = (const int*)  d_in[0];
    const float* emb    = (const float*)d_in[1];
    const float* W_ih0  = (const float*)d_in[2];
    const float* W_hh0  = (const float*)d_in[3];
    const float* b_ih0  = (const float*)d_in[4];
    const float* b_hh0  = (const float*)d_in[5];
    const float* W_ih1  = (const float*)d_in[6];
    const float* W_hh1  = (const float*)d_in[7];
    const float* b_ih1  = (const float*)d_in[8];
    const float* b_hh1  = (const float*)d_in[9];
    const float* W_out  = (const float*)d_in[10];
    const float* b_out  = (const float*)d_in[11];
    float* out = (float*)d_out;

    char* ws = (char*)d_ws;
    _Float16* wimg = (_Float16*)(ws + WIMG_B);
    float* PROJ = (float*)(ws + PROJ_B);

    // zero flags + the t=-1 ring slots (slot 3 of h0 and h1)
    (void)hipMemsetAsync(ws + FLG0_B, 0, 4096, stream);
    (void)hipMemsetAsync(ws + H0_B + (size_t)3 * SLOT * 2, 0, (size_t)SLOT * 2, stream);
    (void)hipMemsetAsync(ws + H1_B + (size_t)3 * SLOT * 2, 0, (size_t)SLOT * 2, stream);

    // pack weight images (role 0: Whh0, role 1: Wih1, role 2: Whh1)
    pack_w<<<512, 256, 0, stream>>>(W_hh0, wimg);
    pack_w<<<512, 256, 0, stream>>>(W_ih1, wimg + (size_t)32 * 65536);
    pack_w<<<512, 256, 0, stream>>>(W_hh1, wimg + (size_t)64 * 65536);
    // fused input projection table (exact f32)
    proj_k<<<512, 256, 0, stream>>>(emb, W_ih0, b_ih0, PROJ);

    // persistent pipelined RNN (192 blocks x 512 threads, flag-array synced)
    rnn_run<<<192, 512, 0, stream>>>(tokens, b_hh0, b_ih1, b_hh1, ws);

    // head from h1[255] (ring slot 3)
    head2<<<128, 256, 0, stream>>>((const _Float16*)(ws + H1_B) + (size_t)3 * SLOT,
                                   W_out, b_out, out);
}